// Round 1
// baseline (41107.593 us; speedup 1.0000x reference)
//
#include <hip/hip_runtime.h>
#include <hip/hip_bf16.h>
#include <stdint.h>

#define NCH  256
#define EMB  1024
#define HID  2048
#define SEQL 4096

// ---------------- ws layout (bytes) ----------------
// Eg   [256][8192] f32 : per-char x-part preactivations (bias included)
// Hs   [4096][2048] f32: all h_t for the final y GEMM
// hbuf [2][2048] f32   : double-buffered h exchange
// cfin [2048] f32      : final cell state
// ctrs [1024] u32      : barrier counters (8 sub @128B spacing + root)
static constexpr size_t EG_OFF   = 0;
static constexpr size_t EG_BYTES = (size_t)NCH * 8192 * 4;          // 8,388,608
static constexpr size_t HS_OFF   = EG_OFF + EG_BYTES;
static constexpr size_t HS_BYTES = (size_t)SEQL * HID * 4;          // 33,554,432
static constexpr size_t HB_OFF   = HS_OFF + HS_BYTES;
static constexpr size_t HB_BYTES = 2 * HID * 4;
static constexpr size_t CF_OFF   = HB_OFF + HB_BYTES;
static constexpr size_t CF_BYTES = HID * 4;
static constexpr size_t CT_OFF   = CF_OFF + CF_BYTES;
static constexpr size_t CT_BYTES = 4096;
static constexpr size_t WS_NEED  = CT_OFF + CT_BYTES;

// ---------------------------------------------------------------------------
// Kernel A: Eg[c][cu*32 + gate*8 + jl] = bias_g[j] + sum_e emb[c][e]*Wg[e][j]
// grid 256 = 64 col-blocks x 4 char-blocks, 256 threads
// ---------------------------------------------------------------------------
__global__ __launch_bounds__(256) void eg_gemm(
    const float* __restrict__ emb,
    const float* __restrict__ Wf, const float* __restrict__ bf,
    const float* __restrict__ Wi, const float* __restrict__ bi,
    const float* __restrict__ Wo, const float* __restrict__ bo,
    const float* __restrict__ Wc, const float* __restrict__ bc,
    float* __restrict__ Eg)
{
    const int nb  = blockIdx.x & 63;   // j block: j in [nb*32, nb*32+32)
    const int cb  = blockIdx.x >> 6;   // chars [cb*64, cb*64+64)
    const int tid = threadIdx.x;
    const int col = tid & 127;         // gate*32 + jj
    const int gate = col >> 5;
    const int jj   = col & 31;
    const int j    = nb * 32 + jj;
    const int mh   = tid >> 7;         // char half (0/1)

    __shared__ float embT[32][65];     // [kk][c]
    __shared__ float Wt[32][128];      // [kk][col]

    float acc[32];
#pragma unroll
    for (int m = 0; m < 32; ++m) acc[m] = 0.f;

    for (int k0 = 0; k0 < EMB; k0 += 32) {
        __syncthreads();
        for (int i = tid; i < 64 * 32; i += 256) {
            int c = i >> 5, kk = i & 31;
            embT[kk][c] = emb[(size_t)(cb * 64 + c) * EMB + k0 + kk];
        }
        for (int i = tid; i < 32 * 128; i += 256) {
            int kk = i >> 7, cl = i & 127;
            int g2 = cl >> 5;
            int jx = nb * 32 + (cl & 31);
            const float* Wp = (g2 == 0) ? Wf : (g2 == 1) ? Wi : (g2 == 2) ? Wo : Wc;
            Wt[kk][cl] = Wp[(size_t)(k0 + kk) * HID + jx];
        }
        __syncthreads();
#pragma unroll 8
        for (int kk = 0; kk < 32; ++kk) {
            float w = Wt[kk][col];
#pragma unroll
            for (int m = 0; m < 32; ++m)
                acc[m] += embT[kk][mh * 32 + m] * w;
        }
    }
    const float* bias = (gate == 0) ? bf : (gate == 1) ? bi : (gate == 2) ? bo : bc;
    float bv = bias[j];
    for (int m = 0; m < 32; ++m) {
        int c = cb * 64 + mh * 32 + m;
        Eg[(size_t)c * 8192 + (j >> 3) * 32 + gate * 8 + (j & 7)] = acc[m] + bv;
    }
}

// ---------------------------------------------------------------------------
// Kernel B: persistent sequential LSTM.
// 256 WGs (1/CU) x 512 threads. Recurrent weights fp32 in VGPRs:
//   thread (wave,lane): dot d = lane&31 (gate=d>>3, jl=d&7, j=cu*8+jl),
//   k-chunk kb = wave*256 + (lane>>5)*128, holds w[q]=Wg[1024+kb+q][j].
// Per step: LDS-broadcast h reads + 128 FMAs -> partial -> reduce ->
// gates on threads 0..7 -> publish h -> 2-level agent-scope barrier -> stage h.
// ---------------------------------------------------------------------------
__global__ __launch_bounds__(512, 2) void lstm_seq(
    const int*   __restrict__ seq,
    const float* __restrict__ h0,
    const float* __restrict__ c0,
    const float* __restrict__ Wf, const float* __restrict__ Wi,
    const float* __restrict__ Wo, const float* __restrict__ Wc,
    const float* __restrict__ Eg,
    float* __restrict__ Hs,
    float* hbuf, float* cfin, unsigned* ctrs)
{
    const int cu   = blockIdx.x;      // 0..255
    const int tid  = threadIdx.x;     // 0..511
    const int lane = tid & 63;
    const int wave = tid >> 6;        // 0..7
    const int d    = lane & 31;       // dot index within CU
    const int half = lane >> 5;       // k half
    const int gate = d >> 3;
    const int jl   = d & 7;
    const int j    = cu * 8 + jl;
    const int kb   = wave * 256 + half * 128;

    const float* W = (gate == 0) ? Wf : (gate == 1) ? Wi : (gate == 2) ? Wo : Wc;

    // ---- load this thread's 128 recurrent weights into registers ----
    float w[128];
#pragma unroll
    for (int q = 0; q < 128; ++q)
        w[q] = W[(size_t)(1024 + kb + q) * HID + j];

    __shared__ float h_lds[2048];
    __shared__ float part[32][17];
    __shared__ float pre_lds[32];

    for (int i = tid; i < HID; i += 512) h_lds[i] = h0[i];
    float c = 0.f;
    if (tid < 8) c = c0[cu * 8 + tid];
    __syncthreads();

    const int grp = cu & 7;
    unsigned* subc = &ctrs[grp * 32];   // 128 B apart
    unsigned* root = &ctrs[8 * 32];

    for (int t = 0; t < SEQL; ++t) {
        // ---- matvec partial: 128 MACs, h via LDS broadcast (float4) ----
        float acc = 0.f;
        const float4* hp = (const float4*)(h_lds + kb);
        // 4 groups of 8 fully-static iterations (keeps w[] indices static,
        // bounds live float4 temps)
#define DOT8(B)                                                              \
        {                                                                    \
            _Pragma("unroll")                                                \
            for (int u = 0; u < 8; ++u) {                                    \
                float4 hv = hp[(B) + u];                                     \
                acc += w[4 * ((B) + u) + 0] * hv.x + w[4 * ((B) + u) + 1] * hv.y \
                     + w[4 * ((B) + u) + 2] * hv.z + w[4 * ((B) + u) + 3] * hv.w; \
            }                                                                \
        }
        DOT8(0) DOT8(8) DOT8(16) DOT8(24)
#undef DOT8
        part[d][wave * 2 + half] = acc;
        __syncthreads();

        // ---- reduce 16 partials + x-part from Eg table ----
        int ct = seq[t];
        if (tid < 32) {
            float s = 0.f;
#pragma unroll
            for (int i = 0; i < 16; ++i) s += part[tid][i];
            pre_lds[tid] = s + Eg[(size_t)ct * 8192 + cu * 32 + tid];
        }
        __syncthreads();

        // ---- gates: threads 0..7 own hidden indices j = cu*8+tid ----
        if (tid < 8) {
            float pf = pre_lds[tid];
            float pi = pre_lds[8 + tid];
            float po = pre_lds[16 + tid];
            float pg = pre_lds[24 + tid];
            float f  = 1.f / (1.f + expf(-pf));
            float ii = 1.f / (1.f + expf(-pi));
            float o  = 1.f / (1.f + expf(-po));
            float g  = tanhf(pg);
            c = f * c + ii * g;
            float hn = o * tanhf(c);
            Hs[(size_t)t * HID + cu * 8 + tid] = hn;
            __hip_atomic_store(&hbuf[((t + 1) & 1) * HID + cu * 8 + tid], hn,
                               __ATOMIC_RELAXED, __HIP_MEMORY_SCOPE_AGENT);
        }
        __syncthreads();

        // ---- global barrier: 8 sub-counters -> root (agent scope) ----
        if (tid == 0) {
            unsigned old = __hip_atomic_fetch_add(subc, 1u, __ATOMIC_ACQ_REL,
                                                  __HIP_MEMORY_SCOPE_AGENT);
            if (old == (unsigned)(32 * (t + 1) - 1))
                __hip_atomic_fetch_add(root, 1u, __ATOMIC_ACQ_REL,
                                       __HIP_MEMORY_SCOPE_AGENT);
            const unsigned target = (unsigned)(8 * (t + 1));
            while (__hip_atomic_load(root, __ATOMIC_RELAXED,
                                     __HIP_MEMORY_SCOPE_AGENT) < target)
                __builtin_amdgcn_s_sleep(1);
            (void)__hip_atomic_load(root, __ATOMIC_ACQUIRE,
                                    __HIP_MEMORY_SCOPE_AGENT);
        }
        __syncthreads();

        // ---- stage h(t+1) into LDS ----
        const float* hb = hbuf + ((t + 1) & 1) * HID;
        for (int i = tid; i < HID; i += 512)
            h_lds[i] = __hip_atomic_load(&hb[i], __ATOMIC_RELAXED,
                                         __HIP_MEMORY_SCOPE_AGENT);
        __syncthreads();
    }

    if (tid < 8) cfin[cu * 8 + tid] = c;
}

// ---------------------------------------------------------------------------
// Kernel C: preds = Hs @ Wy + by.  grid 256 (16 rows/block), 256 threads (col)
// ---------------------------------------------------------------------------
__global__ __launch_bounds__(256) void y_gemm(
    const float* __restrict__ Hs, const float* __restrict__ Wy,
    const float* __restrict__ by, float* __restrict__ out)
{
    const int rb  = blockIdx.x * 16;
    const int tid = threadIdx.x;  // column 0..255
    __shared__ float A[16][68];
    float acc[16];
#pragma unroll
    for (int r = 0; r < 16; ++r) acc[r] = 0.f;

    for (int k0 = 0; k0 < HID; k0 += 64) {
        __syncthreads();
        for (int i = tid; i < 16 * 64; i += 256) {
            int r = i >> 6, kk = i & 63;
            A[r][kk] = Hs[(size_t)(rb + r) * HID + k0 + kk];
        }
        __syncthreads();
#pragma unroll 8
        for (int kk = 0; kk < 64; ++kk) {
            float b = Wy[(size_t)(k0 + kk) * NCH + tid];
#pragma unroll
            for (int r = 0; r < 16; ++r) acc[r] += A[r][kk] * b;
        }
    }
    float bv = by[tid];
    for (int r = 0; r < 16; ++r)
        out[(size_t)(rb + r) * NCH + tid] = acc[r] + bv;
}

// ---------------------------------------------------------------------------
// Kernel D: copy h_fin (= Hs[last]) and c_fin into d_out tail
// ---------------------------------------------------------------------------
__global__ void fin_copy(const float* __restrict__ Hs,
                         const float* __restrict__ cfin,
                         float* __restrict__ out)
{
    int i = blockIdx.x * 256 + threadIdx.x;  // 0..4095
    if (i < HID)
        out[(size_t)SEQL * NCH + i] = Hs[(size_t)(SEQL - 1) * HID + i];
    else
        out[(size_t)SEQL * NCH + i] = cfin[i - HID];
}

// ---------------------------------------------------------------------------
extern "C" void kernel_launch(void* const* d_in, const int* in_sizes, int n_in,
                              void* d_out, int out_size, void* d_ws, size_t ws_size,
                              hipStream_t stream)
{
    if (n_in < 14 || ws_size < WS_NEED) return;  // fail loudly via absmax

    const int*   seq = (const int*)  d_in[0];
    const float* h0  = (const float*)d_in[1];
    const float* c0  = (const float*)d_in[2];
    const float* emb = (const float*)d_in[3];
    const float* Wf  = (const float*)d_in[4];
    const float* bf  = (const float*)d_in[5];
    const float* Wi  = (const float*)d_in[6];
    const float* bi  = (const float*)d_in[7];
    const float* Wo  = (const float*)d_in[8];
    const float* bo  = (const float*)d_in[9];
    const float* Wc  = (const float*)d_in[10];
    const float* bc  = (const float*)d_in[11];
    const float* Wy  = (const float*)d_in[12];
    const float* by  = (const float*)d_in[13];

    char* ws = (char*)d_ws;
    float*    Eg   = (float*)(ws + EG_OFF);
    float*    Hs   = (float*)(ws + HS_OFF);
    float*    hbuf = (float*)(ws + HB_OFF);
    float*    cfin = (float*)(ws + CF_OFF);
    unsigned* ctrs = (unsigned*)(ws + CT_OFF);
    float*    out  = (float*)d_out;

    // reset barrier counters every call (replay-safe)
    hipMemsetAsync(ctrs, 0, CT_BYTES, stream);

    eg_gemm<<<256, 256, 0, stream>>>(emb, Wf, bf, Wi, bi, Wo, bo, Wc, bc, Eg);

    lstm_seq<<<256, 512, 0, stream>>>(seq, h0, c0, Wf, Wi, Wo, Wc, Eg,
                                      Hs, hbuf, cfin, ctrs);

    y_gemm<<<256, 256, 0, stream>>>(Hs, Wy, by, out);

    fin_copy<<<16, 256, 0, stream>>>(Hs, cfin, out);
}